// Round 6
// baseline (2115.836 us; speedup 1.0000x reference)
//
#include <hip/hip_runtime.h>
#include <hip/hip_fp16.h>

#define NT 18
#define NX 160
#define NY 160
#define NPIX (NX*NY)      // 25600
#define NVOX (NT*NPIX)    // 460800

typedef _Float16 __attribute__((ext_vector_type(2))) half2t;
typedef _Float16 __attribute__((ext_vector_type(8))) half8t;
typedef float    __attribute__((ext_vector_type(4))) f32x4;

// ---------------------------------------------------------------------------
__global__ void probe_kernel(float* __restrict__ out, int n, float val) {
  int i = blockIdx.x * 256 + threadIdx.x;
  if (i < n) out[i] = val;
}

// out[k] = xrec[2k]  (extract real plane of interleaved complex)
__global__ void extract_real_kernel(const float* __restrict__ xrec, float* __restrict__ out) {
  int i = blockIdx.x * 256 + threadIdx.x;   // exact: 1800*256 == NVOX
  out[i] = xrec[2 * i];
}

// ---------------------------------------------------------------------------
// DFT matrix G[u][j] = F[(u+80)%160][(j+80)%160], F = ortho DFT(160).
// fft2c(X) = G X G (G symmetric); ifft2c(X) = conj(G) X conj(G).
// ---------------------------------------------------------------------------
__global__ void make_g_kernel(float2* __restrict__ G) {
  int idx = blockIdx.x * 256 + threadIdx.x;
  if (idx >= NPIX) return;
  int r = idx / NY, c = idx - (idx / NY) * NY;
  int rs = (r + 80) % 160;
  int cs = (c + 80) % 160;
  int prod = (rs * cs) % 160;
  double ang = -2.0 * 3.14159265358979323846 * (double)prod / 160.0;
  double sc = 0.07905694150420949;  // 1/sqrt(160)
  G[idx] = make_float2((float)(cos(ang) * sc), (float)(sin(ang) * sc));
}

__global__ void zero_kernel(float* __restrict__ p, int n) {
  int i = blockIdx.x * 256 + threadIdx.x;
  if (i < n) p[i] = 0.f;
}

// out = mask * d   (fp32 re/im planes, int32 mask)
__global__ void mask_d_kernel(const float* __restrict__ dr, const float* __restrict__ di,
                              const int* __restrict__ mask, float2* __restrict__ out) {
  int i = blockIdx.x * 256 + threadIdx.x;
  if (i >= NVOX) return;
  float m = (float)mask[i];
  out[i] = make_float2(m * dr[i], m * di[i]);
}

// out = m*(m*F - d)
__global__ void mask_q_kernel(const float2* __restrict__ F, const float* __restrict__ dr,
                              const float* __restrict__ di, const int* __restrict__ mask,
                              float2* __restrict__ out) {
  int i = blockIdx.x * 256 + threadIdx.x;
  if (i >= NVOX) return;
  float m = (float)mask[i];
  float2 f = F[i];
  out[i] = make_float2(m * (m * f.x - dr[i]), m * (m * f.y - di[i]));
}

// Apply G along last axis, 4 rows per block.
__global__ void fft_pass_last4(const float2* __restrict__ in, float2* __restrict__ out,
                               const float2* __restrict__ G, int conjf) {
  __shared__ float2 rows[4][NY];
  int r0 = blockIdx.x * 4;      // 720 blocks * 4 = NT*NX rows
  int v = threadIdx.x;          // 0..159
#pragma unroll
  for (int r = 0; r < 4; ++r) rows[r][v] = in[(size_t)(r0 + r) * NY + v];
  __syncthreads();
  float sgn = conjf ? -1.f : 1.f;
  float ar0 = 0.f, ai0 = 0.f, ar1 = 0.f, ai1 = 0.f;
  float ar2 = 0.f, ai2 = 0.f, ar3 = 0.f, ai3 = 0.f;
  for (int k = 0; k < NY; ++k) {
    float2 g = G[k * NY + v];
    float gi = sgn * g.y;
    float2 a0 = rows[0][k], a1 = rows[1][k], a2 = rows[2][k], a3 = rows[3][k];
    ar0 += a0.x * g.x - a0.y * gi;  ai0 += a0.x * gi + a0.y * g.x;
    ar1 += a1.x * g.x - a1.y * gi;  ai1 += a1.x * gi + a1.y * g.x;
    ar2 += a2.x * g.x - a2.y * gi;  ai2 += a2.x * gi + a2.y * g.x;
    ar3 += a3.x * g.x - a3.y * gi;  ai3 += a3.x * gi + a3.y * g.x;
  }
  out[(size_t)(r0 + 0) * NY + v] = make_float2(ar0, ai0);
  out[(size_t)(r0 + 1) * NY + v] = make_float2(ar1, ai1);
  out[(size_t)(r0 + 2) * NY + v] = make_float2(ar2, ai2);
  out[(size_t)(r0 + 3) * NY + v] = make_float2(ar3, ai3);
}

// Apply G along middle axis, 4 u-values per block.
__global__ void fft_pass_mid4(const float2* __restrict__ in, float2* __restrict__ out,
                              const float2* __restrict__ G, int conjf) {
  __shared__ float2 grow[4][NX];
  int t = blockIdx.x / 40;              // 18 * 40 = 720 blocks
  int u0 = (blockIdx.x - t * 40) * 4;
  int v = threadIdx.x;
#pragma unroll
  for (int r = 0; r < 4; ++r) grow[r][v] = G[(u0 + r) * NX + v];
  __syncthreads();
  float sgn = conjf ? -1.f : 1.f;
  float ar0 = 0.f, ai0 = 0.f, ar1 = 0.f, ai1 = 0.f;
  float ar2 = 0.f, ai2 = 0.f, ar3 = 0.f, ai3 = 0.f;
  const float2* base = in + (size_t)t * NPIX;
  for (int j = 0; j < NX; ++j) {
    float2 a = base[j * NY + v];
    float2 g0 = grow[0][j], g1 = grow[1][j], g2 = grow[2][j], g3 = grow[3][j];
    float gi0 = sgn * g0.y, gi1 = sgn * g1.y, gi2 = sgn * g2.y, gi3 = sgn * g3.y;
    ar0 += a.x * g0.x - a.y * gi0;  ai0 += a.x * gi0 + a.y * g0.x;
    ar1 += a.x * g1.x - a.y * gi1;  ai1 += a.x * gi1 + a.y * g1.x;
    ar2 += a.x * g2.x - a.y * gi2;  ai2 += a.x * gi2 + a.y * g2.x;
    ar3 += a.x * g3.x - a.y * gi3;  ai3 += a.x * gi3 + a.y * g3.x;
  }
  float2* ob = out + (size_t)t * NPIX + u0 * NY + v;
  ob[0 * NY] = make_float2(ar0, ai0);
  ob[1 * NY] = make_float2(ar1, ai1);
  ob[2 * NY] = make_float2(ar2, ai2);
  ob[3 * NY] = make_float2(ar3, ai3);
}

// R = (1+l2)*xrec - l1*ATAX + l2*(beta - t)
__global__ void rn_kernel(const float* __restrict__ xrec, const float* __restrict__ atax,
                          const float* __restrict__ beta, const float* __restrict__ t,
                          float* __restrict__ R, const float* __restrict__ lam1p,
                          const float* __restrict__ lam2p) {
  int i = blockIdx.x * 256 + threadIdx.x;
  if (i >= 2 * NVOX) return;
  float l1 = fmaxf(lam1p[0], 0.f);
  float l2 = fmaxf(lam2p[0], 0.f);
  R[i] = (1.f + l2) * xrec[i] - l1 * atax[i] + l2 * (beta[i] - t[i]);
}

// soft-threshold on packed half2
__global__ void soft_kernel_h(const __half2* __restrict__ in, __half2* __restrict__ out,
                              const float* __restrict__ thrp, int n2) {
  int i = blockIdx.x * 256 + threadIdx.x;
  if (i >= n2) return;
  float thr = thrp[0];
  float2 f = __half22float2(in[i]);
  float ox = copysignf(fmaxf(fabsf(f.x) - thr, 0.f), f.x);
  float oy = copysignf(fmaxf(fabsf(f.y) - thr, 0.f), f.y);
  out[i] = __floats2half2_rn(ox, oy);
}

// ---------------------------------------------------------------------------
// LDS-staged MFMA conv3d 3x3x3, CIN=16 -> COUT (16 or 2), fp16 NDHWC, SAME.
// Block = (z, y0..y0+1): 20 output tiles of 16 x-voxels; 4 waves x 5 tiles.
// Stage planes z-1..z+1 x rows y0-1..y0+2 x x[-1..160] x 16ch into LDS ONCE
// (coalesced, zero-padded edges) -> A-fragments from LDS. This removes the
// 27x global refetch that made the unstaged version memory-latency-bound
// (403MB/dispatch vs a 4MB per-XCD L2).
// B (weights) in 56 VGPRs/wave.  Fragment layout as verified:
// A/B: lane g=lane>>4 holds 8 contiguous k; C/D col=lane&15, row=g*4+reg.
// ---------------------------------------------------------------------------
template <int COUT, bool RELU, int OUTMODE>
__global__ void __launch_bounds__(256)
conv3d_mfma_kernel(const __half* __restrict__ in_, const float* __restrict__ wts,
                   void* __restrict__ out_, const float* __restrict__ res, float resSign) {
  __shared__ alignas(16) __half lds[12 * 2592];   // 12 rows x 162 vox x 16ch = 62208B
  const int tid = threadIdx.x;
  const int z  = blockIdx.x / 80;                 // grid = 18*80 = 1440
  const int y0 = (blockIdx.x - z * 80) * 2;

  const int lane = tid & 63;
  const int wv = tid >> 6;
  const int n = lane & 15;        // B col (co) / output voxel col
  const int g = lane >> 4;        // k-group (0..3)
  const int sel = g >> 1;         // which tap of the chunk's pair
  const int ci = (g & 1) * 8;     // ci offset within tap

  // B fragments: bw[c][j] = W[k = c*32 + g*8 + j][n], zero-padded
  half8t bw[14];
#pragma unroll
  for (int c = 0; c < 14; ++c) {
#pragma unroll
    for (int j = 0; j < 8; ++j) {
      int kg = c * 32 + g * 8 + j;
      float w = (kg < 432 && n < COUT) ? wts[kg * COUT + n] : 0.f;
      bw[c][j] = (_Float16)w;
    }
  }

  // stage: 12 rows x 324 16B-chunks (2 pad + 320 data + 2 pad per row)
  for (int i = tid; i < 3888; i += 256) {
    int row = i / 324;
    int off = i - row * 324;
    int zz = z - 1 + (row >> 2);
    int yy = y0 - 1 + (row & 3);
    half8t v = {0, 0, 0, 0, 0, 0, 0, 0};
    if (off >= 2 && off < 322 && (unsigned)zz < (unsigned)NT && (unsigned)yy < (unsigned)NX) {
      int xx = (off - 2) >> 1;
      int cih = (off - 2) & 1;
      v = *reinterpret_cast<const half8t*>(
            in_ + ((size_t)((zz * NX + yy) * NY + xx)) * 16 + cih * 8);
    }
    *reinterpret_cast<half8t*>(&lds[row * 2592 + off * 8]) = v;
  }
  __syncthreads();

#pragma unroll 1
  for (int t = 0; t < 5; ++t) {
    int tl = wv * 5 + t;                    // 0..19
    int yloc = (tl >= 10) ? 1 : 0;
    int x0 = (tl - yloc * 10) * 16;

    f32x4 acc = {0.f, 0.f, 0.f, 0.f};
#pragma unroll
    for (int c = 0; c < 14; ++c) {
      const int t0 = 2 * c, t1 = 2 * c + 1;
      const int dz0 = t0 / 9, dy0 = (t0 / 3) % 3, dx0 = t0 % 3;
      const int dz1 = t1 / 9, dy1 = (t1 / 3) % 3, dx1 = t1 % 3;
      half8t a = {0, 0, 0, 0, 0, 0, 0, 0};
      if (c < 13 || !sel) {                 // tap 27 (c==13,sel) = zero pad
        int dz = sel ? dz1 : dz0;
        int dy = sel ? dy1 : dy0;
        int dx = sel ? dx1 : dx0;
        int rowi = dz * 4 + yloc + dy;      // 0..11
        int aoff = rowi * 2592 + (x0 + n + dx) * 16 + ci;   // halves; 16B aligned
        a = *reinterpret_cast<const half8t*>(&lds[aoff]);
      }
      acc = __builtin_amdgcn_mfma_f32_16x16x32_f16(a, bw[c], acc, 0, 0, 0);
    }

    size_t vb = ((size_t)(z * NX) + (y0 + yloc)) * NY + x0;
    if (n < COUT) {
#pragma unroll
      for (int r = 0; r < 4; ++r) {
        float v = acc[r];
        size_t oidx = (vb + g * 4 + r) * COUT + n;
        if (res) v += resSign * res[oidx];
        if (RELU) v = fmaxf(v, 0.f);
        if (OUTMODE == 1) ((__half*)out_)[oidx] = __float2half(v);
        else              ((float*)out_)[oidx] = v;
      }
    }
  }
}

// Generic fp32-input conv (used for the 2->16 first layer only).
struct alignas(16) H8v { half2t h[4]; };

template <int CIN, int COUT, bool RELU, int OUTMODE>
__global__ void __launch_bounds__(256)
conv3d_kernel(const void* __restrict__ in_, const float* __restrict__ wts,
              void* __restrict__ out_, const float* __restrict__ res, float resSign) {
  constexpr int WSZ = 27 * CIN * COUT;
  __shared__ float wl[WSZ];
  for (int i = threadIdx.x; i < WSZ; i += 256) wl[i] = wts[i];
  __syncthreads();
  int gid = blockIdx.x * 256 + threadIdx.x;   // exact: 1800*256 == NVOX
  int d = gid / NPIX;
  int rem = gid - d * NPIX;
  int h = rem / NY;
  int w = rem - h * NY;
  float acc[COUT];
#pragma unroll
  for (int co = 0; co < COUT; ++co) acc[co] = 0.f;
  for (int dz = 0; dz < 3; ++dz) {
    int zz = d + dz - 1;
    if (zz < 0 || zz >= NT) continue;
    for (int dy = 0; dy < 3; ++dy) {
      int yy = h + dy - 1;
      if ((unsigned)yy >= (unsigned)NX) continue;
      for (int dx = 0; dx < 3; ++dx) {
        int xx = w + dx - 1;
        if ((unsigned)xx >= (unsigned)NY) continue;
        size_t voff = (size_t)((zz * NX + yy) * NY + xx) * CIN;
        const float* wp = wl + ((dz * 3 + dy) * 3 + dx) * CIN * COUT;
        float v[CIN];
        const float* p = (const float*)in_ + voff;
#pragma unroll
        for (int k = 0; k < CIN; ++k) v[k] = p[k];
#pragma unroll
        for (int ci = 0; ci < CIN; ++ci) {
#pragma unroll
          for (int co = 0; co < COUT; ++co) acc[co] += v[ci] * wp[ci * COUT + co];
        }
      }
    }
  }
#pragma unroll
  for (int co = 0; co < COUT; ++co) {
    float x = acc[co];
    if (res) x += resSign * res[(size_t)gid * COUT + co];
    if (RELU) x = fmaxf(x, 0.f);
    acc[co] = x;
  }
  if constexpr (OUTMODE == 1) {
    H8v* op = reinterpret_cast<H8v*>((__half*)out_ + (size_t)gid * COUT);
#pragma unroll
    for (int blk = 0; blk < COUT / 8; ++blk) {
      H8v o;
#pragma unroll
      for (int k = 0; k < 4; ++k) {
        o.h[k][0] = (_Float16)acc[blk * 8 + 2 * k];
        o.h[k][1] = (_Float16)acc[blk * 8 + 2 * k + 1];
      }
      op[blk] = o;
    }
  } else {
    float* op = (float*)out_ + (size_t)gid * COUT;
#pragma unroll
    for (int co = 0; co < COUT; ++co) op[co] = acc[co];
  }
}

// ---------------------------------------------------------------------------
// SVD path: t = f(M M^H) M via Gram + parallel-pairs complex Jacobi.
// ---------------------------------------------------------------------------
__global__ void gram_kernel(const float2* __restrict__ M, float2* __restrict__ A) {
  int b = blockIdx.x;  // 0..170 upper-triangular pair
  int i = 0;
  while (b >= NT - i) { b -= NT - i; ++i; }
  int j = i + b;
  int tid = threadIdx.x;
  float sr = 0.f, si = 0.f;
  for (int p = tid; p < NPIX; p += 256) {
    float2 a = M[(size_t)i * NPIX + p];
    float2 c = M[(size_t)j * NPIX + p];
    sr += a.x * c.x + a.y * c.y;   // a * conj(c)
    si += a.y * c.x - a.x * c.y;
  }
  __shared__ float rs[256], is_[256];
  rs[tid] = sr; is_[tid] = si;
  __syncthreads();
  for (int s = 128; s > 0; s >>= 1) {
    if (tid < s) { rs[tid] += rs[tid + s]; is_[tid] += is_[tid + s]; }
    __syncthreads();
  }
  if (tid == 0) {
    A[i * NT + j] = make_float2(rs[0], is_[0]);
    if (i != j) A[j * NT + i] = make_float2(rs[0], -is_[0]);
  }
}

// Parallel-pairs complex Hermitian Jacobi, ONE-PHASE rounds, SINGLE WAVE.
// 64 threads = 1 wave: __syncthreads is near-free (no multi-wave barrier
// scheduling, which dominated the 256/384-thread versions). Each lane owns
// 6 elements of the 18x18 matrices. Same arithmetic as before.
__global__ void __launch_bounds__(64)
eigen_w_kernel(const float2* __restrict__ Ain, const float* __restrict__ tcp,
               float2* __restrict__ Wout) {
  __shared__ float Ar[2][NT][NT], Ai_[2][NT][NT], Vr[2][NT][NT], Vi_[2][NT][NT];
  __shared__ float alR[NT], alI[NT], beR[NT], beI[NT];
  __shared__ float gaR[NT], gaI[NT], deR[NT], deI[NT];
  __shared__ int prt[NT];
  __shared__ float ratio[NT];
  int tid = threadIdx.x;   // 0..63
  for (int idx = tid; idx < NT * NT; idx += 64) {
    int i = idx / NT, j = idx - (idx / NT) * NT;
    float2 a = Ain[idx];
    Ar[0][i][j] = a.x;
    Ai_[0][i][j] = (i == j) ? 0.f : a.y;
    Vr[0][i][j] = (i == j) ? 1.f : 0.f;
    Vi_[0][i][j] = 0.f;
  }
  __syncthreads();
  int cur = 0;
  const int NSWEEP = 8;
  for (int sweep = 0; sweep < NSWEEP; ++sweep) {
    for (int r = 0; r < NT - 1; ++r) {
      if (tid < 9) {
        int k = tid;
        int a = (r + k) % (NT - 1);
        int b = (k == 0) ? (NT - 1) : (r - k + (NT - 1)) % (NT - 1);
        int p = min(a, b), q = max(a, b);
        float apr = Ar[cur][p][q], api = Ai_[cur][p][q];
        float r2 = apr * apr + api * api;
        float c = 1.f, s = 0.f, er = 1.f, ei = 0.f;
        if (r2 > 1e-28f) {
          float inv_r = rsqrtf(r2);
          er = apr * inv_r; ei = api * inv_r;          // e = apq/|apq|
          float th = (Ar[cur][q][q] - Ar[cur][p][p]) * 0.5f * inv_r;
          float tt = (th >= 0.f ? 1.f : -1.f) / (fabsf(th) + sqrtf(th * th + 1.f));
          c = rsqrtf(tt * tt + 1.f);
          s = tt * c;
        }
        prt[p] = q; prt[q] = p;
        alR[p] = c;       alI[p] = 0.f;     beR[p] = -s * er;  beI[p] =  s * ei;
        alR[q] = c * er;  alI[q] = -c * ei; beR[q] = s;        beI[q] = 0.f;
        gaR[p] = c;       gaI[p] = 0.f;     deR[p] = -s * er;  deI[p] = -s * ei;
        gaR[q] = c * er;  gaI[q] = c * ei;  deR[q] = s;        deI[q] = 0.f;
      }
      __syncthreads();
#pragma unroll
      for (int k6 = 0; k6 < 6; ++k6) {
        int idx = tid + k6 * 64;
        if (idx < NT * NT) {
          int i = idx / NT, j = idx - (idx / NT) * NT;
          int pj = prt[j], pi = prt[i];
          float aR = alR[j], aI = alI[j], bR = beR[j], bI = beI[j];
          float x0r = Ar[cur][i][j],   x0i = Ai_[cur][i][j];
          float x1r = Ar[cur][i][pj],  x1i = Ai_[cur][i][pj];
          float y0r = Ar[cur][pi][j],  y0i = Ai_[cur][pi][j];
          float y1r = Ar[cur][pi][pj], y1i = Ai_[cur][pi][pj];
          float B0r = aR * x0r - aI * x0i + bR * x1r - bI * x1i;
          float B0i = aR * x0i + aI * x0r + bR * x1i + bI * x1r;
          float B1r = aR * y0r - aI * y0i + bR * y1r - bI * y1i;
          float B1i = aR * y0i + aI * y0r + bR * y1i + bI * y1r;
          float gR = gaR[i], gI = gaI[i], dR = deR[i], dI = deI[i];
          Ar[cur ^ 1][i][j]  = gR * B0r - gI * B0i + dR * B1r - dI * B1i;
          Ai_[cur ^ 1][i][j] = gR * B0i + gI * B0r + dR * B1i + dI * B1r;
          float v0r = Vr[cur][i][j],  v0i = Vi_[cur][i][j];
          float v1r = Vr[cur][i][pj], v1i = Vi_[cur][i][pj];
          Vr[cur ^ 1][i][j] = aR * v0r - aI * v0i + bR * v1r - bI * v1i;
          Vi_[cur ^ 1][i][j] = aR * v0i + aI * v0r + bR * v1i + bI * v1r;
        }
      }
      __syncthreads();
      cur ^= 1;
    }
  }
  if (tid == 0) {
    float smax = 0.f;
    for (int k = 0; k < NT; ++k) {
      float sv = sqrtf(fmaxf(Ar[cur][k][k], 0.f));
      ratio[k] = sv;
      smax = fmaxf(smax, sv);
    }
    float sig = 1.f / (1.f + expf(-tcp[0]));
    float thres = sig * smax;
    for (int k = 0; k < NT; ++k) {
      float sv = ratio[k];
      ratio[k] = (sv > thres) ? (sv - thres) / sv : 0.f;
    }
  }
  __syncthreads();
  for (int idx = tid; idx < NT * NT; idx += 64) {
    int i = idx / NT, j = idx - (idx / NT) * NT;
    float wr = 0.f, wi = 0.f;
    for (int k = 0; k < NT; ++k) {
      float rk = ratio[k];
      wr += rk * (Vr[cur][i][k] * Vr[cur][j][k] + Vi_[cur][i][k] * Vi_[cur][j][k]);
      wi += rk * (Vi_[cur][i][k] * Vr[cur][j][k] - Vr[cur][i][k] * Vi_[cur][j][k]);
    }
    Wout[idx] = make_float2(wr, wi);
  }
}

// t = W M;  beta += eta*(M - t)
__global__ void svd_apply_kernel(const float2* __restrict__ M, const float2* __restrict__ Wm,
                                 float2* __restrict__ t, float2* __restrict__ beta,
                                 const float* __restrict__ etap) {
  __shared__ float2 W[NT * NT];
  int tid = threadIdx.x;
  for (int i = tid; i < NT * NT; i += 256) W[i] = Wm[i];
  __syncthreads();
  int p = blockIdx.x * 256 + tid;  // exact: 100*256 == NPIX
  float eta = fmaxf(etap[0], 0.f);
  float2 m[NT];
#pragma unroll
  for (int j = 0; j < NT; ++j) m[j] = M[(size_t)j * NPIX + p];
#pragma unroll
  for (int i = 0; i < NT; ++i) {
    float tr = 0.f, ti = 0.f;
#pragma unroll
    for (int j = 0; j < NT; ++j) {
      float2 w = W[i * NT + j];
      tr += w.x * m[j].x - w.y * m[j].y;
      ti += w.x * m[j].y + w.y * m[j].x;
    }
    t[(size_t)i * NPIX + p] = make_float2(tr, ti);
    float2 b = beta[(size_t)i * NPIX + p];
    b.x += eta * (m[i].x - tr);
    b.y += eta * (m[i].y - ti);
    beta[(size_t)i * NPIX + p] = b;
  }
}

// ---------------------------------------------------------------------------
extern "C" void kernel_launch(void* const* d_in, const int* in_sizes, int n_in,
                              void* d_out, int out_size, void* d_ws, size_t ws_size,
                              hipStream_t stream) {
  // Inputs fp32; mask int32. Output fp32, layout:
  //   out[0 : 460800]                  = real(x_rec)
  //   out[460800 + 921600*i : +921600] = X_SYM[i]
  const float* d_real    = (const float*)d_in[0];
  const float* d_imag    = (const float*)d_in[1];
  const int*   mask      = (const int*)d_in[2];
  const float* W1        = (const float*)d_in[3];
  const float* W2        = (const float*)d_in[4];
  const float* W3        = (const float*)d_in[5];
  const float* W4        = (const float*)d_in[6];
  const float* W5        = (const float*)d_in[7];
  const float* W6        = (const float*)d_in[8];
  const float* lam1      = (const float*)d_in[9];
  const float* lam2      = (const float*)d_in[10];
  const float* soft_thr  = (const float*)d_in[11];
  const float* thres_c   = (const float*)d_in[12];
  const float* eta       = (const float*)d_in[13];
  float* out = (float*)d_out;
  (void)in_sizes; (void)n_in;

  const size_t NEEDED = 59400000ull;
  if (ws_size < NEEDED) {
    probe_kernel<<<(out_size + 255) / 256, 256, 0, stream>>>(out, out_size,
                                                             (float)(ws_size >> 20));
    return;
  }

  char* wp_ = (char*)d_ws;
  auto alloc = [&](size_t bytes) {
    char* r = wp_;
    wp_ += (bytes + 255) & ~(size_t)255;
    return r;
  };
  float2* G     = (float2*)alloc((size_t)NPIX * sizeof(float2));
  float2* xrec  = (float2*)alloc((size_t)NVOX * sizeof(float2));
  float2* tbuf  = (float2*)alloc((size_t)NVOX * sizeof(float2));
  float2* beta  = (float2*)alloc((size_t)NVOX * sizeof(float2));
  float*  Rf    = (float*)alloc((size_t)NVOX * 2 * sizeof(float));
  __half* Af    = (__half*)alloc((size_t)NVOX * 16 * sizeof(__half));
  __half* Bf    = (__half*)alloc((size_t)NVOX * 16 * sizeof(__half));
  __half* Cf    = (__half*)alloc((size_t)NVOX * 16 * sizeof(__half));
  float2* Agram = (float2*)alloc((size_t)NT * NT * sizeof(float2));
  float2* Wmat  = (float2*)alloc((size_t)NT * NT * sizeof(float2));
  float2* T1 = (float2*)Af;
  float2* T2 = (float2*)Bf;

  make_g_kernel<<<100, 256, 0, stream>>>(G);
  zero_kernel<<<3600, 256, 0, stream>>>((float*)tbuf, 2 * NVOX);
  zero_kernel<<<3600, 256, 0, stream>>>((float*)beta, 2 * NVOX);

  // x_rec = ifft2c(mask * d)
  mask_d_kernel<<<1800, 256, 0, stream>>>(d_real, d_imag, mask, T1);
  fft_pass_last4<<<720, 160, 0, stream>>>(T1, T2, G, 1);
  fft_pass_mid4<<<720, 160, 0, stream>>>(T2, xrec, G, 1);

  for (int i = 0; i < 3; ++i) {
    // ATAX = ifft2c(m*(m*fft2c(x_rec) - d))
    fft_pass_last4<<<720, 160, 0, stream>>>(xrec, T1, G, 0);
    fft_pass_mid4<<<720, 160, 0, stream>>>(T1, T2, G, 0);
    mask_q_kernel<<<1800, 256, 0, stream>>>(T2, d_real, d_imag, mask, T1);
    fft_pass_last4<<<720, 160, 0, stream>>>(T1, T2, G, 1);
    fft_pass_mid4<<<720, 160, 0, stream>>>(T2, T1, G, 1);   // ATAX in T1
    rn_kernel<<<3600, 256, 0, stream>>>((const float*)xrec, (const float*)T1,
                                        (const float*)beta, (const float*)tbuf,
                                        Rf, lam1 + i, lam2 + i);
    // main conv chain (fp16 activations; CIN=16 layers on staged MFMA)
    conv3d_kernel<2, 16, true, 1><<<1800, 256, 0, stream>>>(
        Rf, W1 + (size_t)i * 864, Af, nullptr, 0.f);
    conv3d_mfma_kernel<16, true, 1><<<1440, 256, 0, stream>>>(
        Af, W2 + (size_t)i * 6912, Bf, nullptr, 0.f);
    conv3d_mfma_kernel<16, false, 1><<<1440, 256, 0, stream>>>(
        Bf, W3 + (size_t)i * 6912, Cf, nullptr, 0.f);
    soft_kernel_h<<<14400, 256, 0, stream>>>((const __half2*)Cf, (__half2*)Af,
                                             soft_thr + i, NVOX * 8);
    conv3d_mfma_kernel<16, true, 1><<<1440, 256, 0, stream>>>(
        Af, W4 + (size_t)i * 6912, Bf, nullptr, 0.f);
    conv3d_mfma_kernel<16, true, 1><<<1440, 256, 0, stream>>>(
        Bf, W5 + (size_t)i * 6912, Af, nullptr, 0.f);
    // x_out = conv + r -> xrec (interleaved complex, fp32)
    conv3d_mfma_kernel<2, false, 0><<<1440, 256, 0, stream>>>(
        Af, W6 + (size_t)i * 864, (float*)xrec, Rf, 1.f);
    // x_sym branch (from x3 = Cf) -> out[460800 + 921600*i ...]
    conv3d_mfma_kernel<16, true, 1><<<1440, 256, 0, stream>>>(
        Cf, W4 + (size_t)i * 6912, Bf, nullptr, 0.f);
    conv3d_mfma_kernel<16, true, 1><<<1440, 256, 0, stream>>>(
        Bf, W5 + (size_t)i * 6912, Af, nullptr, 0.f);
    conv3d_mfma_kernel<2, false, 0><<<1440, 256, 0, stream>>>(
        Af, W6 + (size_t)i * 864, out + 460800 + (size_t)921600 * i, Rf, -1.f);
    // low-rank step (results unused after last iteration -> skip)
    if (i < 2) {
      gram_kernel<<<171, 256, 0, stream>>>((const float2*)xrec, Agram);
      eigen_w_kernel<<<1, 64, 0, stream>>>(Agram, thres_c + i, Wmat);
      svd_apply_kernel<<<100, 256, 0, stream>>>((const float2*)xrec, Wmat, tbuf, beta, eta + i);
    }
  }
  // out[0:460800] = real(x_rec final)
  extract_real_kernel<<<1800, 256, 0, stream>>>((const float*)xrec, out);
}

// Round 7
// 1830.746 us; speedup vs baseline: 1.1557x; 1.1557x over previous
//
#include <hip/hip_runtime.h>
#include <hip/hip_fp16.h>

#define NT 18
#define NX 160
#define NY 160
#define NPIX (NX*NY)      // 25600
#define NVOX (NT*NPIX)    // 460800

typedef _Float16 __attribute__((ext_vector_type(2))) half2t;
typedef _Float16 __attribute__((ext_vector_type(8))) half8t;
typedef float    __attribute__((ext_vector_type(4))) f32x4;

// ---------------------------------------------------------------------------
__global__ void probe_kernel(float* __restrict__ out, int n, float val) {
  int i = blockIdx.x * 256 + threadIdx.x;
  if (i < n) out[i] = val;
}

// out[k] = xrec[2k]  (extract real plane of interleaved complex)
__global__ void extract_real_kernel(const float* __restrict__ xrec, float* __restrict__ out) {
  int i = blockIdx.x * 256 + threadIdx.x;   // exact: 1800*256 == NVOX
  out[i] = xrec[2 * i];
}

// ---------------------------------------------------------------------------
// DFT matrix G[u][j] = F[(u+80)%160][(j+80)%160], F = ortho DFT(160).
// fft2c(X) = G X G (G symmetric); ifft2c(X) = conj(G) X conj(G).
// ---------------------------------------------------------------------------
__global__ void make_g_kernel(float2* __restrict__ G) {
  int idx = blockIdx.x * 256 + threadIdx.x;
  if (idx >= NPIX) return;
  int r = idx / NY, c = idx - (idx / NY) * NY;
  int rs = (r + 80) % 160;
  int cs = (c + 80) % 160;
  int prod = (rs * cs) % 160;
  double ang = -2.0 * 3.14159265358979323846 * (double)prod / 160.0;
  double sc = 0.07905694150420949;  // 1/sqrt(160)
  G[idx] = make_float2((float)(cos(ang) * sc), (float)(sin(ang) * sc));
}

__global__ void zero_kernel(float* __restrict__ p, int n) {
  int i = blockIdx.x * 256 + threadIdx.x;
  if (i < n) p[i] = 0.f;
}

// out = mask * d   (fp32 re/im planes, int32 mask)
__global__ void mask_d_kernel(const float* __restrict__ dr, const float* __restrict__ di,
                              const int* __restrict__ mask, float2* __restrict__ out) {
  int i = blockIdx.x * 256 + threadIdx.x;
  if (i >= NVOX) return;
  float m = (float)mask[i];
  out[i] = make_float2(m * dr[i], m * di[i]);
}

// out = m*(m*F - d)
__global__ void mask_q_kernel(const float2* __restrict__ F, const float* __restrict__ dr,
                              const float* __restrict__ di, const int* __restrict__ mask,
                              float2* __restrict__ out) {
  int i = blockIdx.x * 256 + threadIdx.x;
  if (i >= NVOX) return;
  float m = (float)mask[i];
  float2 f = F[i];
  out[i] = make_float2(m * (m * f.x - dr[i]), m * (m * f.y - di[i]));
}

// Apply G along last axis, 4 rows per block.
__global__ void fft_pass_last4(const float2* __restrict__ in, float2* __restrict__ out,
                               const float2* __restrict__ G, int conjf) {
  __shared__ float2 rows[4][NY];
  int r0 = blockIdx.x * 4;      // 720 blocks * 4 = NT*NX rows
  int v = threadIdx.x;          // 0..159
#pragma unroll
  for (int r = 0; r < 4; ++r) rows[r][v] = in[(size_t)(r0 + r) * NY + v];
  __syncthreads();
  float sgn = conjf ? -1.f : 1.f;
  float ar0 = 0.f, ai0 = 0.f, ar1 = 0.f, ai1 = 0.f;
  float ar2 = 0.f, ai2 = 0.f, ar3 = 0.f, ai3 = 0.f;
  for (int k = 0; k < NY; ++k) {
    float2 g = G[k * NY + v];
    float gi = sgn * g.y;
    float2 a0 = rows[0][k], a1 = rows[1][k], a2 = rows[2][k], a3 = rows[3][k];
    ar0 += a0.x * g.x - a0.y * gi;  ai0 += a0.x * gi + a0.y * g.x;
    ar1 += a1.x * g.x - a1.y * gi;  ai1 += a1.x * gi + a1.y * g.x;
    ar2 += a2.x * g.x - a2.y * gi;  ai2 += a2.x * gi + a2.y * g.x;
    ar3 += a3.x * g.x - a3.y * gi;  ai3 += a3.x * gi + a3.y * g.x;
  }
  out[(size_t)(r0 + 0) * NY + v] = make_float2(ar0, ai0);
  out[(size_t)(r0 + 1) * NY + v] = make_float2(ar1, ai1);
  out[(size_t)(r0 + 2) * NY + v] = make_float2(ar2, ai2);
  out[(size_t)(r0 + 3) * NY + v] = make_float2(ar3, ai3);
}

// Apply G along middle axis, 4 u-values per block.
__global__ void fft_pass_mid4(const float2* __restrict__ in, float2* __restrict__ out,
                              const float2* __restrict__ G, int conjf) {
  __shared__ float2 grow[4][NX];
  int t = blockIdx.x / 40;              // 18 * 40 = 720 blocks
  int u0 = (blockIdx.x - t * 40) * 4;
  int v = threadIdx.x;
#pragma unroll
  for (int r = 0; r < 4; ++r) grow[r][v] = G[(u0 + r) * NX + v];
  __syncthreads();
  float sgn = conjf ? -1.f : 1.f;
  float ar0 = 0.f, ai0 = 0.f, ar1 = 0.f, ai1 = 0.f;
  float ar2 = 0.f, ai2 = 0.f, ar3 = 0.f, ai3 = 0.f;
  const float2* base = in + (size_t)t * NPIX;
  for (int j = 0; j < NX; ++j) {
    float2 a = base[j * NY + v];
    float2 g0 = grow[0][j], g1 = grow[1][j], g2 = grow[2][j], g3 = grow[3][j];
    float gi0 = sgn * g0.y, gi1 = sgn * g1.y, gi2 = sgn * g2.y, gi3 = sgn * g3.y;
    ar0 += a.x * g0.x - a.y * gi0;  ai0 += a.x * gi0 + a.y * g0.x;
    ar1 += a.x * g1.x - a.y * gi1;  ai1 += a.x * gi1 + a.y * g1.x;
    ar2 += a.x * g2.x - a.y * gi2;  ai2 += a.x * gi2 + a.y * g2.x;
    ar3 += a.x * g3.x - a.y * gi3;  ai3 += a.x * gi3 + a.y * g3.x;
  }
  float2* ob = out + (size_t)t * NPIX + u0 * NY + v;
  ob[0 * NY] = make_float2(ar0, ai0);
  ob[1 * NY] = make_float2(ar1, ai1);
  ob[2 * NY] = make_float2(ar2, ai2);
  ob[3 * NY] = make_float2(ar3, ai3);
}

// R = (1+l2)*xrec - l1*ATAX + l2*(beta - t)
__global__ void rn_kernel(const float* __restrict__ xrec, const float* __restrict__ atax,
                          const float* __restrict__ beta, const float* __restrict__ t,
                          float* __restrict__ R, const float* __restrict__ lam1p,
                          const float* __restrict__ lam2p) {
  int i = blockIdx.x * 256 + threadIdx.x;
  if (i >= 2 * NVOX) return;
  float l1 = fmaxf(lam1p[0], 0.f);
  float l2 = fmaxf(lam2p[0], 0.f);
  R[i] = (1.f + l2) * xrec[i] - l1 * atax[i] + l2 * (beta[i] - t[i]);
}

// ---------------------------------------------------------------------------
// LDS-staged MFMA conv3d 3x3x3, CIN=16 -> COUT (16 or 2), fp16 NDHWC, SAME.
// Block = (z, y0..y0+1): 20 output tiles of 16 x-voxels; 4 waves x 5 tiles.
// SOFT: apply soft-threshold (sign(x)*relu(|x|-thr)) during staging — fuses
// the former soft_kernel dispatch + buffer round-trip into this kernel.
// ---------------------------------------------------------------------------
template <int COUT, bool RELU, int OUTMODE, bool SOFT>
__global__ void __launch_bounds__(256)
conv3d_mfma_kernel(const __half* __restrict__ in_, const float* __restrict__ wts,
                   void* __restrict__ out_, const float* __restrict__ res, float resSign,
                   const float* __restrict__ thrp) {
  __shared__ alignas(16) __half lds[12 * 2592];   // 12 rows x 162 vox x 16ch = 62208B
  const int tid = threadIdx.x;
  const int z  = blockIdx.x / 80;                 // grid = 18*80 = 1440
  const int y0 = (blockIdx.x - z * 80) * 2;

  const int lane = tid & 63;
  const int wv = tid >> 6;
  const int n = lane & 15;        // B col (co) / output voxel col
  const int g = lane >> 4;        // k-group (0..3)
  const int sel = g >> 1;         // which tap of the chunk's pair
  const int ci = (g & 1) * 8;     // ci offset within tap

  // B fragments: bw[c][j] = W[k = c*32 + g*8 + j][n], zero-padded
  half8t bw[14];
#pragma unroll
  for (int c = 0; c < 14; ++c) {
#pragma unroll
    for (int j = 0; j < 8; ++j) {
      int kg = c * 32 + g * 8 + j;
      float w = (kg < 432 && n < COUT) ? wts[kg * COUT + n] : 0.f;
      bw[c][j] = (_Float16)w;
    }
  }

  float thr = SOFT ? thrp[0] : 0.f;

  // stage: 12 rows x 324 16B-chunks (2 pad + 320 data + 2 pad per row)
  for (int i = tid; i < 3888; i += 256) {
    int row = i / 324;
    int off = i - row * 324;
    int zz = z - 1 + (row >> 2);
    int yy = y0 - 1 + (row & 3);
    half8t v = {0, 0, 0, 0, 0, 0, 0, 0};
    if (off >= 2 && off < 322 && (unsigned)zz < (unsigned)NT && (unsigned)yy < (unsigned)NX) {
      int xx = (off - 2) >> 1;
      int cih = (off - 2) & 1;
      v = *reinterpret_cast<const half8t*>(
            in_ + ((size_t)((zz * NX + yy) * NY + xx)) * 16 + cih * 8);
      if (SOFT) {
#pragma unroll
        for (int e = 0; e < 8; ++e) {
          float f = (float)v[e];
          v[e] = (_Float16)copysignf(fmaxf(fabsf(f) - thr, 0.f), f);
        }
      }
    }
    *reinterpret_cast<half8t*>(&lds[row * 2592 + off * 8]) = v;
  }
  __syncthreads();

#pragma unroll 1
  for (int t = 0; t < 5; ++t) {
    int tl = wv * 5 + t;                    // 0..19
    int yloc = (tl >= 10) ? 1 : 0;
    int x0 = (tl - yloc * 10) * 16;

    f32x4 acc = {0.f, 0.f, 0.f, 0.f};
#pragma unroll
    for (int c = 0; c < 14; ++c) {
      const int t0 = 2 * c, t1 = 2 * c + 1;
      const int dz0 = t0 / 9, dy0 = (t0 / 3) % 3, dx0 = t0 % 3;
      const int dz1 = t1 / 9, dy1 = (t1 / 3) % 3, dx1 = t1 % 3;
      half8t a = {0, 0, 0, 0, 0, 0, 0, 0};
      if (c < 13 || !sel) {                 // tap 27 (c==13,sel) = zero pad
        int dz = sel ? dz1 : dz0;
        int dy = sel ? dy1 : dy0;
        int dx = sel ? dx1 : dx0;
        int rowi = dz * 4 + yloc + dy;      // 0..11
        int aoff = rowi * 2592 + (x0 + n + dx) * 16 + ci;   // halves; 16B aligned
        a = *reinterpret_cast<const half8t*>(&lds[aoff]);
      }
      acc = __builtin_amdgcn_mfma_f32_16x16x32_f16(a, bw[c], acc, 0, 0, 0);
    }

    size_t vb = ((size_t)(z * NX) + (y0 + yloc)) * NY + x0;
    if (n < COUT) {
#pragma unroll
      for (int r = 0; r < 4; ++r) {
        float v = acc[r];
        size_t oidx = (vb + g * 4 + r) * COUT + n;
        if (res) v += resSign * res[oidx];
        if (RELU) v = fmaxf(v, 0.f);
        if (OUTMODE == 1) ((__half*)out_)[oidx] = __float2half(v);
        else              ((float*)out_)[oidx] = v;
      }
    }
  }
}

// Generic fp32-input conv (used for the 2->16 first layer only).
struct alignas(16) H8v { half2t h[4]; };

template <int CIN, int COUT, bool RELU, int OUTMODE>
__global__ void __launch_bounds__(256)
conv3d_kernel(const void* __restrict__ in_, const float* __restrict__ wts,
              void* __restrict__ out_, const float* __restrict__ res, float resSign) {
  constexpr int WSZ = 27 * CIN * COUT;
  __shared__ float wl[WSZ];
  for (int i = threadIdx.x; i < WSZ; i += 256) wl[i] = wts[i];
  __syncthreads();
  int gid = blockIdx.x * 256 + threadIdx.x;   // exact: 1800*256 == NVOX
  int d = gid / NPIX;
  int rem = gid - d * NPIX;
  int h = rem / NY;
  int w = rem - h * NY;
  float acc[COUT];
#pragma unroll
  for (int co = 0; co < COUT; ++co) acc[co] = 0.f;
  for (int dz = 0; dz < 3; ++dz) {
    int zz = d + dz - 1;
    if (zz < 0 || zz >= NT) continue;
    for (int dy = 0; dy < 3; ++dy) {
      int yy = h + dy - 1;
      if ((unsigned)yy >= (unsigned)NX) continue;
      for (int dx = 0; dx < 3; ++dx) {
        int xx = w + dx - 1;
        if ((unsigned)xx >= (unsigned)NY) continue;
        size_t voff = (size_t)((zz * NX + yy) * NY + xx) * CIN;
        const float* wp = wl + ((dz * 3 + dy) * 3 + dx) * CIN * COUT;
        float v[CIN];
        const float* p = (const float*)in_ + voff;
#pragma unroll
        for (int k = 0; k < CIN; ++k) v[k] = p[k];
#pragma unroll
        for (int ci = 0; ci < CIN; ++ci) {
#pragma unroll
          for (int co = 0; co < COUT; ++co) acc[co] += v[ci] * wp[ci * COUT + co];
        }
      }
    }
  }
#pragma unroll
  for (int co = 0; co < COUT; ++co) {
    float x = acc[co];
    if (res) x += resSign * res[(size_t)gid * COUT + co];
    if (RELU) x = fmaxf(x, 0.f);
    acc[co] = x;
  }
  if constexpr (OUTMODE == 1) {
    H8v* op = reinterpret_cast<H8v*>((__half*)out_ + (size_t)gid * COUT);
#pragma unroll
    for (int blk = 0; blk < COUT / 8; ++blk) {
      H8v o;
#pragma unroll
      for (int k = 0; k < 4; ++k) {
        o.h[k][0] = (_Float16)acc[blk * 8 + 2 * k];
        o.h[k][1] = (_Float16)acc[blk * 8 + 2 * k + 1];
      }
      op[blk] = o;
    }
  } else {
    float* op = (float*)out_ + (size_t)gid * COUT;
#pragma unroll
    for (int co = 0; co < COUT; ++co) op[co] = acc[co];
  }
}

// ---------------------------------------------------------------------------
// SVD path: t = f(M M^H) M via Gram + parallel-pairs complex Jacobi.
// ---------------------------------------------------------------------------
__global__ void gram_kernel(const float2* __restrict__ M, float2* __restrict__ A) {
  int b = blockIdx.x;  // 0..170 upper-triangular pair
  int i = 0;
  while (b >= NT - i) { b -= NT - i; ++i; }
  int j = i + b;
  int tid = threadIdx.x;
  float sr = 0.f, si = 0.f;
  for (int p = tid; p < NPIX; p += 256) {
    float2 a = M[(size_t)i * NPIX + p];
    float2 c = M[(size_t)j * NPIX + p];
    sr += a.x * c.x + a.y * c.y;   // a * conj(c)
    si += a.y * c.x - a.x * c.y;
  }
  __shared__ float rs[256], is_[256];
  rs[tid] = sr; is_[tid] = si;
  __syncthreads();
  for (int s = 128; s > 0; s >>= 1) {
    if (tid < s) { rs[tid] += rs[tid + s]; is_[tid] += is_[tid + s]; }
    __syncthreads();
  }
  if (tid == 0) {
    A[i * NT + j] = make_float2(rs[0], is_[0]);
    if (i != j) A[j * NT + i] = make_float2(rs[0], -is_[0]);
  }
}

// Parallel-pairs (tournament) complex Hermitian Jacobi — 3-phase, 256 threads.
// Measured-best structure (112us): one item per thread per phase.
__global__ void __launch_bounds__(256)
eigen_w_kernel(const float2* __restrict__ Ain, const float* __restrict__ tcp,
               float2* __restrict__ Wout) {
  __shared__ float Ar[NT][NT], Ai_[NT][NT], Vr[NT][NT], Vi_[NT][NT];
  __shared__ float cS[9], sS[9], erS[9], eiS[9];
  __shared__ int pS[9], qS[9];
  __shared__ float ratio[NT];
  int tid = threadIdx.x;
  for (int idx = tid; idx < NT * NT; idx += 256) {
    int i = idx / NT, j = idx - (idx / NT) * NT;
    float2 a = Ain[idx];
    Ar[i][j] = a.x;
    Ai_[i][j] = (i == j) ? 0.f : a.y;
    Vr[i][j] = (i == j) ? 1.f : 0.f;
    Vi_[i][j] = 0.f;
  }
  __syncthreads();
  const int NSWEEP = 8;
  for (int sweep = 0; sweep < NSWEEP; ++sweep) {
    for (int r = 0; r < NT - 1; ++r) {
      // phase 1: rotation params for 9 disjoint pairs (circle method)
      if (tid < 9) {
        int k = tid;
        int a = (r + k) % (NT - 1);
        int b = (k == 0) ? (NT - 1) : (r - k + (NT - 1)) % (NT - 1);
        int p = min(a, b), q = max(a, b);
        pS[k] = p; qS[k] = q;
        float apr = Ar[p][q], api = Ai_[p][q];
        float r2 = apr * apr + api * api;
        float c = 1.f, s = 0.f, er = 1.f, ei = 0.f;
        if (r2 > 1e-28f) {
          float rr = sqrtf(r2);
          float inv_r = 1.f / rr;
          er = apr * inv_r; ei = api * inv_r;          // e = apq/|apq|
          float th = (Ar[q][q] - Ar[p][p]) * 0.5f * inv_r;
          float tt = (th >= 0.f ? 1.f : -1.f) / (fabsf(th) + sqrtf(th * th + 1.f));
          c = 1.f / sqrtf(tt * tt + 1.f);
          s = tt * c;
        }
        cS[k] = c; sS[k] = s; erS[k] = er; eiS[k] = ei;
      }
      __syncthreads();
      // phase 2: column update  B = A*J  and  V = V*J   (162 disjoint items)
      if (tid < 9 * NT) {
        int idx = tid;
        int k = idx / 9, j = idx - (idx / 9) * 9;
        int p = pS[j], q = qS[j];
        float c = cS[j], s = sS[j], er = erS[j], ei = eiS[j];
        float apr = Ar[k][p], api = Ai_[k][p];
        float aqr = Ar[k][q], aqi = Ai_[k][q];
        float eqr = er * aqr + ei * aqi;               // conj(e)*a_q
        float eqi = er * aqi - ei * aqr;
        Ar[k][p] = c * apr - s * eqr;  Ai_[k][p] = c * api - s * eqi;
        Ar[k][q] = s * apr + c * eqr;  Ai_[k][q] = s * api + c * eqi;
        float vpr = Vr[k][p], vpi = Vi_[k][p];
        float vqr = Vr[k][q], vqi = Vi_[k][q];
        float evr = er * vqr + ei * vqi;
        float evi = er * vqi - ei * vqr;
        Vr[k][p] = c * vpr - s * evr;  Vi_[k][p] = c * vpi - s * evi;
        Vr[k][q] = s * vpr + c * evr;  Vi_[k][q] = s * vpi + c * evi;
      }
      __syncthreads();
      // phase 3: row update  A' = J^H * B   (162 disjoint items)
      if (tid < 9 * NT) {
        int idx = tid;
        int k = idx / 9, j = idx - (idx / 9) * 9;
        int p = pS[j], q = qS[j];
        float c = cS[j], s = sS[j], er = erS[j], ei = eiS[j];
        float bpr = Ar[p][k], bpi = Ai_[p][k];
        float bqr = Ar[q][k], bqi = Ai_[q][k];
        float ebr = er * bqr - ei * bqi;               // e*b_q
        float ebi = er * bqi + ei * bqr;
        Ar[p][k] = c * bpr - s * ebr;  Ai_[p][k] = c * bpi - s * ebi;
        Ar[q][k] = s * bpr + c * ebr;  Ai_[q][k] = s * bpi + c * ebi;
      }
      __syncthreads();
    }
  }
  if (tid == 0) {
    float smax = 0.f;
    for (int k = 0; k < NT; ++k) {
      float sv = sqrtf(fmaxf(Ar[k][k], 0.f));
      ratio[k] = sv;
      smax = fmaxf(smax, sv);
    }
    float sig = 1.f / (1.f + expf(-tcp[0]));
    float thres = sig * smax;
    for (int k = 0; k < NT; ++k) {
      float sv = ratio[k];
      ratio[k] = (sv > thres) ? (sv - thres) / sv : 0.f;
    }
  }
  __syncthreads();
  for (int idx = tid; idx < NT * NT; idx += 256) {
    int i = idx / NT, j = idx - (idx / NT) * NT;
    float wr = 0.f, wi = 0.f;
    for (int k = 0; k < NT; ++k) {
      float rk = ratio[k];
      wr += rk * (Vr[i][k] * Vr[j][k] + Vi_[i][k] * Vi_[j][k]);
      wi += rk * (Vi_[i][k] * Vr[j][k] - Vr[i][k] * Vi_[j][k]);
    }
    Wout[idx] = make_float2(wr, wi);
  }
}

// t = W M;  beta += eta*(M - t)
__global__ void svd_apply_kernel(const float2* __restrict__ M, const float2* __restrict__ Wm,
                                 float2* __restrict__ t, float2* __restrict__ beta,
                                 const float* __restrict__ etap) {
  __shared__ float2 W[NT * NT];
  int tid = threadIdx.x;
  for (int i = tid; i < NT * NT; i += 256) W[i] = Wm[i];
  __syncthreads();
  int p = blockIdx.x * 256 + tid;  // exact: 100*256 == NPIX
  float eta = fmaxf(etap[0], 0.f);
  float2 m[NT];
#pragma unroll
  for (int j = 0; j < NT; ++j) m[j] = M[(size_t)j * NPIX + p];
#pragma unroll
  for (int i = 0; i < NT; ++i) {
    float tr = 0.f, ti = 0.f;
#pragma unroll
    for (int j = 0; j < NT; ++j) {
      float2 w = W[i * NT + j];
      tr += w.x * m[j].x - w.y * m[j].y;
      ti += w.x * m[j].y + w.y * m[j].x;
    }
    t[(size_t)i * NPIX + p] = make_float2(tr, ti);
    float2 b = beta[(size_t)i * NPIX + p];
    b.x += eta * (m[i].x - tr);
    b.y += eta * (m[i].y - ti);
    beta[(size_t)i * NPIX + p] = b;
  }
}

// ---------------------------------------------------------------------------
extern "C" void kernel_launch(void* const* d_in, const int* in_sizes, int n_in,
                              void* d_out, int out_size, void* d_ws, size_t ws_size,
                              hipStream_t stream) {
  // Inputs fp32; mask int32. Output fp32, layout:
  //   out[0 : 460800]                  = real(x_rec)
  //   out[460800 + 921600*i : +921600] = X_SYM[i]
  const float* d_real    = (const float*)d_in[0];
  const float* d_imag    = (const float*)d_in[1];
  const int*   mask      = (const int*)d_in[2];
  const float* W1        = (const float*)d_in[3];
  const float* W2        = (const float*)d_in[4];
  const float* W3        = (const float*)d_in[5];
  const float* W4        = (const float*)d_in[6];
  const float* W5        = (const float*)d_in[7];
  const float* W6        = (const float*)d_in[8];
  const float* lam1      = (const float*)d_in[9];
  const float* lam2      = (const float*)d_in[10];
  const float* soft_thr  = (const float*)d_in[11];
  const float* thres_c   = (const float*)d_in[12];
  const float* eta       = (const float*)d_in[13];
  float* out = (float*)d_out;
  (void)in_sizes; (void)n_in;

  const size_t NEEDED = 59400000ull;
  if (ws_size < NEEDED) {
    probe_kernel<<<(out_size + 255) / 256, 256, 0, stream>>>(out, out_size,
                                                             (float)(ws_size >> 20));
    return;
  }

  char* wp_ = (char*)d_ws;
  auto alloc = [&](size_t bytes) {
    char* r = wp_;
    wp_ += (bytes + 255) & ~(size_t)255;
    return r;
  };
  float2* G     = (float2*)alloc((size_t)NPIX * sizeof(float2));
  float2* xrec  = (float2*)alloc((size_t)NVOX * sizeof(float2));
  float2* tbuf  = (float2*)alloc((size_t)NVOX * sizeof(float2));
  float2* beta  = (float2*)alloc((size_t)NVOX * sizeof(float2));   // contiguous after tbuf
  float*  Rf    = (float*)alloc((size_t)NVOX * 2 * sizeof(float));
  __half* Af    = (__half*)alloc((size_t)NVOX * 16 * sizeof(__half));
  __half* Bf    = (__half*)alloc((size_t)NVOX * 16 * sizeof(__half));
  __half* Cf    = (__half*)alloc((size_t)NVOX * 16 * sizeof(__half));
  float2* Agram = (float2*)alloc((size_t)NT * NT * sizeof(float2));
  float2* Wmat  = (float2*)alloc((size_t)NT * NT * sizeof(float2));
  float2* T1 = (float2*)Af;
  float2* T2 = (float2*)Bf;

  make_g_kernel<<<100, 256, 0, stream>>>(G);
  zero_kernel<<<7200, 256, 0, stream>>>((float*)tbuf, 4 * NVOX);  // tbuf + beta

  // x_rec = ifft2c(mask * d)
  mask_d_kernel<<<1800, 256, 0, stream>>>(d_real, d_imag, mask, T1);
  fft_pass_last4<<<720, 160, 0, stream>>>(T1, T2, G, 1);
  fft_pass_mid4<<<720, 160, 0, stream>>>(T2, xrec, G, 1);

  for (int i = 0; i < 3; ++i) {
    // ATAX = ifft2c(m*(m*fft2c(x_rec) - d))
    fft_pass_last4<<<720, 160, 0, stream>>>(xrec, T1, G, 0);
    fft_pass_mid4<<<720, 160, 0, stream>>>(T1, T2, G, 0);
    mask_q_kernel<<<1800, 256, 0, stream>>>(T2, d_real, d_imag, mask, T1);
    fft_pass_last4<<<720, 160, 0, stream>>>(T1, T2, G, 1);
    fft_pass_mid4<<<720, 160, 0, stream>>>(T2, T1, G, 1);   // ATAX in T1
    rn_kernel<<<3600, 256, 0, stream>>>((const float*)xrec, (const float*)T1,
                                        (const float*)beta, (const float*)tbuf,
                                        Rf, lam1 + i, lam2 + i);
    // main conv chain (fp16 activations; CIN=16 layers on staged MFMA)
    conv3d_kernel<2, 16, true, 1><<<1800, 256, 0, stream>>>(
        Rf, W1 + (size_t)i * 864, Af, nullptr, 0.f);
    conv3d_mfma_kernel<16, true, 1, false><<<1440, 256, 0, stream>>>(
        Af, W2 + (size_t)i * 6912, Bf, nullptr, 0.f, nullptr);
    conv3d_mfma_kernel<16, false, 1, false><<<1440, 256, 0, stream>>>(
        Bf, W3 + (size_t)i * 6912, Cf, nullptr, 0.f, nullptr);
    // W4 on soft(x3): threshold fused into staging (reads Cf directly)
    conv3d_mfma_kernel<16, true, 1, true><<<1440, 256, 0, stream>>>(
        Cf, W4 + (size_t)i * 6912, Bf, nullptr, 0.f, soft_thr + i);
    conv3d_mfma_kernel<16, true, 1, false><<<1440, 256, 0, stream>>>(
        Bf, W5 + (size_t)i * 6912, Af, nullptr, 0.f, nullptr);
    // x_out = conv + r -> xrec (interleaved complex, fp32)
    conv3d_mfma_kernel<2, false, 0, false><<<1440, 256, 0, stream>>>(
        Af, W6 + (size_t)i * 864, (float*)xrec, Rf, 1.f, nullptr);
    // x_sym branch (from x3 = Cf, unthresholded) -> out[460800 + 921600*i ...]
    conv3d_mfma_kernel<16, true, 1, false><<<1440, 256, 0, stream>>>(
        Cf, W4 + (size_t)i * 6912, Bf, nullptr, 0.f, nullptr);
    conv3d_mfma_kernel<16, true, 1, false><<<1440, 256, 0, stream>>>(
        Bf, W5 + (size_t)i * 6912, Af, nullptr, 0.f, nullptr);
    conv3d_mfma_kernel<2, false, 0, false><<<1440, 256, 0, stream>>>(
        Af, W6 + (size_t)i * 864, out + 460800 + (size_t)921600 * i, Rf, -1.f, nullptr);
    // low-rank step (results unused after last iteration -> skip)
    if (i < 2) {
      gram_kernel<<<171, 256, 0, stream>>>((const float2*)xrec, Agram);
      eigen_w_kernel<<<1, 256, 0, stream>>>(Agram, thres_c + i, Wmat);
      svd_apply_kernel<<<100, 256, 0, stream>>>((const float2*)xrec, Wmat, tbuf, beta, eta + i);
    }
  }
  // out[0:460800] = real(x_rec final)
  extract_real_kernel<<<1800, 256, 0, stream>>>((const float*)xrec, out);
}